// Round 3
// baseline (1327.213 us; speedup 1.0000x reference)
//
#include <hip/hip_runtime.h>
#include <math.h>

#define BLK 256

// ---------------- init: deg=1 (self loop), acc=0, zacc=0 ----------------
__global__ void k_init(int* __restrict__ deg, float* __restrict__ acc,
                       float* __restrict__ zacc, int n, int accn, int ng) {
  int j = blockIdx.x * BLK + threadIdx.x;
  if (j < accn) acc[j] = 0.f;
  if (j < n) deg[j] = 1;
  if (j < ng) zacc[j] = 0.f;
}

// ---------------- degree count over dst ----------------
__global__ void k_deg(const int* __restrict__ dst, int* __restrict__ deg, int E) {
  int i = blockIdx.x * BLK + threadIdx.x;
  if (i < E) atomicAdd(&deg[dst[i]], 1);
}

// ---------------- prefix scan over (deg-1): block-local exclusive + block sums ----------------
__global__ void k_scan1(const int* __restrict__ deg, int* __restrict__ rowptr,
                        int* __restrict__ bsum, int n) {
  __shared__ int sd[BLK];
  int t = threadIdx.x;
  int i = blockIdx.x * BLK + t;
  int v = (i < n) ? (deg[i] - 1) : 0;
  sd[t] = v; __syncthreads();
  int inc = v;
  for (int off = 1; off < BLK; off <<= 1) {
    int u = (t >= off) ? sd[t - off] : 0; __syncthreads();
    inc += u; sd[t] = inc; __syncthreads();
  }
  if (i < n) rowptr[i] = inc - v;           // local exclusive
  if (t == BLK - 1) bsum[blockIdx.x] = inc; // block total
}

// ---------------- scan of block sums (single block, serial carry) ----------------
__global__ void k_scan2(int* __restrict__ bsum, int nb) {
  __shared__ int sd[BLK];
  __shared__ int stot;
  int t = threadIdx.x;
  int carry = 0;
  for (int c = 0; c < nb; c += BLK) {
    int v = (c + t < nb) ? bsum[c + t] : 0;
    sd[t] = v; __syncthreads();
    int inc = v;
    for (int off = 1; off < BLK; off <<= 1) {
      int u = (t >= off) ? sd[t - off] : 0; __syncthreads();
      inc += u; sd[t] = inc; __syncthreads();
    }
    if (t == BLK - 1) stot = inc;
    __syncthreads();
    if (c + t < nb) bsum[c + t] = carry + inc - v;  // global exclusive
    carry += stot;
    __syncthreads();
  }
}

// ---------------- add block offsets; init cursor ----------------
__global__ void k_scan3(int* __restrict__ rowptr, int* __restrict__ cursor,
                        const int* __restrict__ bsum, int n) {
  int i = blockIdx.x * BLK + threadIdx.x;
  if (i < n) {
    int r = rowptr[i] + bsum[blockIdx.x];
    rowptr[i] = r;
    cursor[i] = r;
  }
}

// ---------------- CSR fill: csr[slot(dst)] = src ----------------
__global__ void k_fill(const int* __restrict__ src, const int* __restrict__ dst,
                       int* __restrict__ cursor, int* __restrict__ csr, int E) {
  int e = blockIdx.x * BLK + threadIdx.x;
  if (e < E) {
    int slot = atomicAdd(&cursor[dst[e]], 1);
    csr[slot] = src[e];
  }
}

// ---------------- gather: acc[d][h] = sum over in-edges of y[src][h] ----------------
__global__ void k_gather(const int* __restrict__ rowptr, const int* __restrict__ csr,
                         const float* __restrict__ y, float* __restrict__ acc,
                         int n, int E) {
  int t = blockIdx.x * BLK + threadIdx.x;
  int node = t >> 3;
  int h = t & 7;
  if (node >= n) return;
  int start = rowptr[node];
  int end = (node == n - 1) ? E : rowptr[node + 1];
  float s = 0.f;
  int si = (start < end) ? csr[start] : 0;
  for (int k = start; k < end; ++k) {
    int nsi = (k + 1 < end) ? csr[k + 1] : 0;  // prefetch next src idx
    s += y[(size_t)si * 8 + h];
    si = nsi;
  }
  acc[(size_t)node * 8 + h] = s;
}

// ---------------- y1 = dis * (x @ W1); deg buffer becomes dis (in place) ----------------
__global__ void k_y1(const float* __restrict__ x, const float* __restrict__ W1,
                     int* __restrict__ degdis, float* __restrict__ y, int n) {
  __shared__ float sW[128];
  if (threadIdx.x < 128) sW[threadIdx.x] = W1[threadIdx.x];
  __syncthreads();
  int i = blockIdx.x * BLK + threadIdx.x;
  if (i >= n) return;
  const float4* xp = (const float4*)(x + (size_t)i * 16);
  float4 a = xp[0], b = xp[1], c = xp[2], d4 = xp[3];
  float xv[16] = {a.x,a.y,a.z,a.w, b.x,b.y,b.z,b.w,
                  c.x,c.y,c.z,c.w, d4.x,d4.y,d4.z,d4.w};
  float dis = rsqrtf((float)degdis[i]);
  float o[8];
  #pragma unroll
  for (int j = 0; j < 8; ++j) {
    float s = 0.f;
    #pragma unroll
    for (int k = 0; k < 16; ++k) s = fmaf(xv[k], sW[k*8 + j], s);
    o[j] = dis * s;
  }
  ((float*)degdis)[i] = dis;   // overwrite deg with dis (own element only)
  float4* yp = (float4*)(y + (size_t)i * 8);
  yp[0] = make_float4(o[0], o[1], o[2], o[3]);
  yp[1] = make_float4(o[4], o[5], o[6], o[7]);
}

// ---------------- legacy edge scatter (fallback if ws too small) ----------------
__global__ void k_scatter(const int* __restrict__ src, const int* __restrict__ dst,
                          const float* __restrict__ y, float* __restrict__ acc,
                          long long total) {
  long long t = (long long)blockIdx.x * BLK + threadIdx.x;
  if (t >= total) return;
  int e = (int)(t >> 3);
  int h = (int)(t & 7);
  int s = src[e], d = dst[e];
  unsafeAtomicAdd(&acc[(size_t)d * 8 + h], y[(size_t)s * 8 + h]);
}

// ---------------- h1 = relu(dis*(acc+y)+b1); y <- dis*(h1@W2); acc <- 0 ----------------
__global__ void k_mid(const float* __restrict__ dis, float* __restrict__ y,
                      float* __restrict__ acc, const float* __restrict__ W2,
                      const float* __restrict__ b1, int n, int zero_acc) {
  __shared__ float sW[64];
  __shared__ float sb[8];
  if (threadIdx.x < 64) sW[threadIdx.x] = W2[threadIdx.x];
  if (threadIdx.x < 8)  sb[threadIdx.x] = b1[threadIdx.x];
  __syncthreads();
  int i = blockIdx.x * BLK + threadIdx.x;
  if (i >= n) return;
  float d = dis[i];
  float4* yp = (float4*)(y + (size_t)i * 8);
  float4* ap = (float4*)(acc + (size_t)i * 8);
  float4 y0 = yp[0], y1v = yp[1], a0 = ap[0], a1 = ap[1];
  float yy[8] = {y0.x,y0.y,y0.z,y0.w, y1v.x,y1v.y,y1v.z,y1v.w};
  float aa[8] = {a0.x,a0.y,a0.z,a0.w, a1.x,a1.y,a1.z,a1.w};
  float hv[8];
  #pragma unroll
  for (int j = 0; j < 8; ++j) hv[j] = fmaxf(fmaf(d, yy[j] + aa[j], sb[j]), 0.f);
  float o[8];
  #pragma unroll
  for (int j = 0; j < 8; ++j) {
    float s = 0.f;
    #pragma unroll
    for (int k = 0; k < 8; ++k) s = fmaf(hv[k], sW[k*8 + j], s);
    o[j] = d * s;
  }
  yp[0] = make_float4(o[0], o[1], o[2], o[3]);
  yp[1] = make_float4(o[4], o[5], o[6], o[7]);
  if (zero_acc) {
    ap[0] = make_float4(0.f, 0.f, 0.f, 0.f);
    ap[1] = make_float4(0.f, 0.f, 0.f, 0.f);
  }
}

// ---------------- h2 = relu(dis*(acc+y)+b2); zacc[batch[i]] += h2 . Wl ----------------
__global__ void k_final(const float* __restrict__ dis, const float* __restrict__ y,
                        const float* __restrict__ acc, const float* __restrict__ b2,
                        const float* __restrict__ Wl, const int* __restrict__ batch,
                        float* __restrict__ zacc, int n) {
  __shared__ float sb[8], sw[8];
  if (threadIdx.x < 8) { sb[threadIdx.x] = b2[threadIdx.x]; sw[threadIdx.x] = Wl[threadIdx.x]; }
  __syncthreads();
  int i = blockIdx.x * BLK + threadIdx.x;
  float s = 0.f;
  int g = -1;
  if (i < n) {
    float d = dis[i];
    const float4* yp = (const float4*)(y + (size_t)i * 8);
    const float4* ap = (const float4*)(acc + (size_t)i * 8);
    float4 y0 = yp[0], y1v = yp[1], a0 = ap[0], a1 = ap[1];
    float yy[8] = {y0.x,y0.y,y0.z,y0.w, y1v.x,y1v.y,y1v.z,y1v.w};
    float aa[8] = {a0.x,a0.y,a0.z,a0.w, a1.x,a1.y,a1.z,a1.w};
    #pragma unroll
    for (int j = 0; j < 8; ++j) {
      float h = fmaxf(fmaf(d, yy[j] + aa[j], sb[j]), 0.f);
      s = fmaf(h, sw[j], s);
    }
    g = batch[i];
  }
  int g0 = __shfl(g, 0);
  bool uni = __all(g == g0);
  if (uni) {
    #pragma unroll
    for (int off = 32; off > 0; off >>= 1) s += __shfl_down(s, off);
    if ((threadIdx.x & 63) == 0 && g0 >= 0) unsafeAtomicAdd(&zacc[g0], s);
  } else if (i < n) {
    unsafeAtomicAdd(&zacc[g], s);
  }
}

// ---------------- out = sigmoid(zacc + bl) ----------------
__global__ void k_out(const float* __restrict__ zacc, const float* __restrict__ bl,
                      float* __restrict__ out, int ng) {
  int i = blockIdx.x * BLK + threadIdx.x;
  if (i < ng) {
    float z = zacc[i] + bl[0];
    float r;
    if (z >= 0.f) { r = 1.f / (1.f + expf(-z)); }
    else          { float e = expf(z); r = e / (1.f + e); }
    out[i] = r;
  }
}

static inline size_t alignup(size_t v) { return (v + 255) & ~(size_t)255; }

extern "C" void kernel_launch(void* const* d_in, const int* in_sizes, int n_in,
                              void* d_out, int out_size, void* d_ws, size_t ws_size,
                              hipStream_t stream) {
  const float* x   = (const float*)d_in[0];
  const int*   ei  = (const int*)  d_in[1];
  const int*   bat = (const int*)  d_in[2];
  const float* W1  = (const float*)d_in[3];
  const float* b1  = (const float*)d_in[4];
  const float* W2  = (const float*)d_in[5];
  const float* b2  = (const float*)d_in[6];
  const float* Wl  = (const float*)d_in[7];
  const float* bl  = (const float*)d_in[8];
  float* out = (float*)d_out;

  int n  = in_sizes[0] / 16;   // 250000
  int E  = in_sizes[1] / 2;    // 8000000
  int ng = out_size;           // 512

  const int* src = ei;
  const int* dst = ei + E;

  char* wsb = (char*)d_ws;
  size_t offY  = alignup((size_t)n * 4);
  size_t offA  = offY + alignup((size_t)n * 32 / 8 * 8);      // y: n*8 floats
  size_t offZ  = offA + alignup((size_t)n * 32 / 8 * 8);      // acc: n*8 floats
  size_t offRP = offZ + alignup((size_t)ng * 4);
  size_t offCu = offRP + alignup(((size_t)n + 1) * 4);
  size_t offBs = offCu + alignup((size_t)n * 4);
  size_t offCs = offBs + alignup(4096);
  size_t need  = offCs + alignup((size_t)E * 4);

  int*   deg    = (int*)wsb;
  float* dis    = (float*)wsb;
  float* y      = (float*)(wsb + offY);
  float* acc    = (float*)(wsb + offA);
  float* zacc   = (float*)(wsb + offZ);
  int*   rowptr = (int*)(wsb + offRP);
  int*   cursor = (int*)(wsb + offCu);
  int*   bsum   = (int*)(wsb + offBs);
  int*   csr    = (int*)(wsb + offCs);

  int accn = n * 8;
  int gInit = (accn + BLK - 1) / BLK;
  int gE    = (E + BLK - 1) / BLK;
  int gN    = (n + BLK - 1) / BLK;
  int gG    = (ng + BLK - 1) / BLK;
  int nb    = gN;                      // number of scan blocks
  int gT    = (accn + BLK - 1) / BLK;  // node*8 threads for gather

  bool csr_path = (ws_size >= need) && (nb <= 1024);

  k_init<<<gInit, BLK, 0, stream>>>(deg, acc, zacc, n, accn, ng);
  k_deg<<<gE, BLK, 0, stream>>>(dst, deg, E);

  if (csr_path) {
    k_scan1<<<nb, BLK, 0, stream>>>(deg, rowptr, bsum, n);
    k_scan2<<<1, BLK, 0, stream>>>(bsum, nb);
    k_scan3<<<nb, BLK, 0, stream>>>(rowptr, cursor, bsum, n);
    k_fill<<<gE, BLK, 0, stream>>>(src, dst, cursor, csr, E);
    k_y1<<<gN, BLK, 0, stream>>>(x, W1, deg, y, n);
    k_gather<<<gT, BLK, 0, stream>>>(rowptr, csr, y, acc, n, E);
    k_mid<<<gN, BLK, 0, stream>>>(dis, y, acc, W2, b1, n, 0);
    k_gather<<<gT, BLK, 0, stream>>>(rowptr, csr, y, acc, n, E);
    k_final<<<gN, BLK, 0, stream>>>(dis, y, acc, b2, Wl, bat, zacc, n);
  } else {
    long long tot = (long long)E * 8;
    int gS = (int)((tot + BLK - 1) / BLK);
    k_y1<<<gN, BLK, 0, stream>>>(x, W1, deg, y, n);
    k_scatter<<<gS, BLK, 0, stream>>>(src, dst, y, acc, tot);
    k_mid<<<gN, BLK, 0, stream>>>(dis, y, acc, W2, b1, n, 1);
    k_scatter<<<gS, BLK, 0, stream>>>(src, dst, y, acc, tot);
    k_final<<<gN, BLK, 0, stream>>>(dis, y, acc, b2, Wl, bat, zacc, n);
  }
  k_out<<<gG, BLK, 0, stream>>>(zacc, bl, out, ng);
}

// Round 5
// 905.119 us; speedup vs baseline: 1.4663x; 1.4663x over previous
//
#include <hip/hip_runtime.h>
#include <math.h>

#define BLK 256
#define CH 8192          // edges per k_bin block
#define NBMAX 1024       // max buckets (256 nodes each)

// ================= new binned path =================

// zero ghist + zacc
__global__ void k_init0(int* __restrict__ ghist, float* __restrict__ zacc,
                        int nb, int ng) {
  int i = blockIdx.x * BLK + threadIdx.x;
  if (i < nb) ghist[i] = 0;
  if (i < ng) zacc[i] = 0.f;
}

// per-bucket histogram of dst>>8
__global__ void k_hist(const int* __restrict__ dst, int* __restrict__ ghist,
                       int E, int nb, int chunk) {
  __shared__ int h[NBMAX];
  for (int i = threadIdx.x; i < NBMAX; i += BLK) h[i] = 0;
  __syncthreads();
  long long s0 = (long long)blockIdx.x * chunk;
  int c = (int)min((long long)chunk, (long long)E - s0);
  for (int i = threadIdx.x; i < c; i += BLK)
    atomicAdd(&h[dst[s0 + i] >> 8], 1);
  __syncthreads();
  for (int b = threadIdx.x; b < nb; b += BLK)
    if (h[b]) atomicAdd(&ghist[b], h[b]);
}

// exclusive scan of ghist -> base[0..nb], cursor=base
__global__ void k_scan(const int* __restrict__ ghist, int* __restrict__ base,
                       int* __restrict__ cursor, int nb, int E) {
  __shared__ int temp[BLK];
  int t = threadIdx.x;
  int v[4]; int sm = 0;
  #pragma unroll
  for (int k = 0; k < 4; ++k) {
    int idx = t * 4 + k;
    v[k] = (idx < nb) ? ghist[idx] : 0;
    sm += v[k];
  }
  temp[t] = sm; __syncthreads();
  int inc = sm;
  for (int off = 1; off < BLK; off <<= 1) {
    int u = (t >= off) ? temp[t - off] : 0; __syncthreads();
    inc += u; temp[t] = inc; __syncthreads();
  }
  int run = inc - sm;
  #pragma unroll
  for (int k = 0; k < 4; ++k) {
    int idx = t * 4 + k;
    if (idx < nb) { base[idx] = run; cursor[idx] = run; }
    run += v[k];
  }
  if (t == BLK - 1) base[nb] = E;
}

// bin edges into per-bucket segments, packed rec = (src<<8)|(dst&255)
__global__ void k_bin(const int* __restrict__ src, const int* __restrict__ dst,
                      int* __restrict__ cursor, int* __restrict__ binned,
                      int E, int nb) {
  __shared__ int cnt[NBMAX], cur[NBMAX], gofs[NBMAX], baseA[NBMAX + 1], temp[BLK];
  __shared__ int stage[CH];
  int t = threadIdx.x;
  for (int i = t; i < NBMAX; i += BLK) { cnt[i] = 0; cur[i] = 0; }
  __syncthreads();
  long long s0 = (long long)blockIdx.x * CH;
  int c = (int)min((long long)CH, (long long)E - s0);
  for (int i = t; i < c; i += BLK) atomicAdd(&cnt[dst[s0 + i] >> 8], 1);
  __syncthreads();
  // local exclusive scan of cnt -> baseA
  int v[4], sm = 0;
  #pragma unroll
  for (int k = 0; k < 4; ++k) { v[k] = cnt[t * 4 + k]; sm += v[k]; }
  temp[t] = sm; __syncthreads();
  int inc = sm;
  for (int off = 1; off < BLK; off <<= 1) {
    int u = (t >= off) ? temp[t - off] : 0; __syncthreads();
    inc += u; temp[t] = inc; __syncthreads();
  }
  int run = inc - sm;
  #pragma unroll
  for (int k = 0; k < 4; ++k) { baseA[t * 4 + k] = run; run += v[k]; }
  if (t == BLK - 1) baseA[NBMAX] = c;
  __syncthreads();
  // reserve global ranges
  for (int b = t; b < nb; b += BLK)
    if (cnt[b]) gofs[b] = atomicAdd(&cursor[b], cnt[b]);
  __syncthreads();
  // place records into staging, bucket-grouped
  for (int i = t; i < c; i += BLK) {
    int d = dst[s0 + i];
    int b = d >> 8;
    int r = atomicAdd(&cur[b], 1);
    stage[baseA[b] + r] = (src[s0 + i] << 8) | (d & 255);
  }
  __syncthreads();
  // flush runs (binary search bucket of slot i)
  for (int i = t; i < c; i += BLK) {
    int lo = 0, hi = nb;
    while (hi - lo > 1) { int m = (lo + hi) >> 1; if (baseA[m] <= i) lo = m; else hi = m; }
    binned[(size_t)gofs[lo] + (i - baseA[lo])] = stage[i];
  }
}

// per-bucket degree (incl. self-loop) -> dis = rsqrt(deg)
__global__ void k_degdis(const int* __restrict__ base, const int* __restrict__ binned,
                         float* __restrict__ dis, int n) {
  __shared__ int deg[256];
  int b = blockIdx.x, t = threadIdx.x;
  deg[t] = 1;
  __syncthreads();
  int s = base[b], e = base[b + 1];
  for (int i = s + t; i < e; i += BLK) atomicAdd(&deg[binned[i] & 255], 1);
  __syncthreads();
  int node = b * 256 + t;
  if (node < n) dis[node] = rsqrtf((float)deg[t]);
}

// per-bucket accumulate: acc[node][j] = sum of y[src][j] over in-edges (LDS atomics)
__global__ void k_acc(const int* __restrict__ base, const int* __restrict__ binned,
                      const float* __restrict__ y, float* __restrict__ acc, int n) {
  __shared__ float fa[2048];
  int b = blockIdx.x, t = threadIdx.x;
  for (int i = t; i < 2048; i += BLK) fa[i] = 0.f;
  __syncthreads();
  int s = base[b], e = base[b + 1];
  int j = t & 7;
  for (int i = s + (t >> 3); i < e; i += 32) {
    int rec = binned[i];
    atomicAdd(&fa[(rec & 255) * 8 + j], y[(size_t)(rec >> 8) * 8 + j]);
  }
  __syncthreads();
  int node0 = b * 256;
  int lim = (n - node0 < 256 ? n - node0 : 256) * 8;
  for (int i = t; i < lim; i += BLK) acc[(size_t)node0 * 8 + i] = fa[i];
}

// y1 = dis * (x @ W1), dis precomputed
__global__ void k_y1n(const float* __restrict__ x, const float* __restrict__ W1,
                      const float* __restrict__ dis, float* __restrict__ y, int n) {
  __shared__ float sW[128];
  if (threadIdx.x < 128) sW[threadIdx.x] = W1[threadIdx.x];
  __syncthreads();
  int i = blockIdx.x * BLK + threadIdx.x;
  if (i >= n) return;
  const float4* xp = (const float4*)(x + (size_t)i * 16);
  float4 a = xp[0], bb = xp[1], cc = xp[2], d4 = xp[3];
  float xv[16] = {a.x,a.y,a.z,a.w, bb.x,bb.y,bb.z,bb.w,
                  cc.x,cc.y,cc.z,cc.w, d4.x,d4.y,d4.z,d4.w};
  float ds = dis[i];
  float o[8];
  #pragma unroll
  for (int jj = 0; jj < 8; ++jj) {
    float s = 0.f;
    #pragma unroll
    for (int k = 0; k < 16; ++k) s = fmaf(xv[k], sW[k*8 + jj], s);
    o[jj] = ds * s;
  }
  float4* yp = (float4*)(y + (size_t)i * 8);
  yp[0] = make_float4(o[0], o[1], o[2], o[3]);
  yp[1] = make_float4(o[4], o[5], o[6], o[7]);
}

// ================= shared tail kernels =================

__global__ void k_mid(const float* __restrict__ dis, float* __restrict__ y,
                      float* __restrict__ acc, const float* __restrict__ W2,
                      const float* __restrict__ b1, int n, int zero_acc) {
  __shared__ float sW[64];
  __shared__ float sb[8];
  if (threadIdx.x < 64) sW[threadIdx.x] = W2[threadIdx.x];
  if (threadIdx.x < 8)  sb[threadIdx.x] = b1[threadIdx.x];
  __syncthreads();
  int i = blockIdx.x * BLK + threadIdx.x;
  if (i >= n) return;
  float d = dis[i];
  float4* yp = (float4*)(y + (size_t)i * 8);
  float4* ap = (float4*)(acc + (size_t)i * 8);
  float4 y0 = yp[0], y1v = yp[1], a0 = ap[0], a1 = ap[1];
  float yy[8] = {y0.x,y0.y,y0.z,y0.w, y1v.x,y1v.y,y1v.z,y1v.w};
  float aa[8] = {a0.x,a0.y,a0.z,a0.w, a1.x,a1.y,a1.z,a1.w};
  float hv[8];
  #pragma unroll
  for (int jj = 0; jj < 8; ++jj) hv[jj] = fmaxf(fmaf(d, yy[jj] + aa[jj], sb[jj]), 0.f);
  float o[8];
  #pragma unroll
  for (int jj = 0; jj < 8; ++jj) {
    float s = 0.f;
    #pragma unroll
    for (int k = 0; k < 8; ++k) s = fmaf(hv[k], sW[k*8 + jj], s);
    o[jj] = d * s;
  }
  yp[0] = make_float4(o[0], o[1], o[2], o[3]);
  yp[1] = make_float4(o[4], o[5], o[6], o[7]);
  if (zero_acc) {
    ap[0] = make_float4(0.f, 0.f, 0.f, 0.f);
    ap[1] = make_float4(0.f, 0.f, 0.f, 0.f);
  }
}

__global__ void k_final(const float* __restrict__ dis, const float* __restrict__ y,
                        const float* __restrict__ acc, const float* __restrict__ b2,
                        const float* __restrict__ Wl, const int* __restrict__ batch,
                        float* __restrict__ zacc, int n) {
  __shared__ float sb[8], sw[8];
  if (threadIdx.x < 8) { sb[threadIdx.x] = b2[threadIdx.x]; sw[threadIdx.x] = Wl[threadIdx.x]; }
  __syncthreads();
  int i = blockIdx.x * BLK + threadIdx.x;
  float s = 0.f;
  int g = -1;
  if (i < n) {
    float d = dis[i];
    const float4* yp = (const float4*)(y + (size_t)i * 8);
    const float4* ap = (const float4*)(acc + (size_t)i * 8);
    float4 y0 = yp[0], y1v = yp[1], a0 = ap[0], a1 = ap[1];
    float yy[8] = {y0.x,y0.y,y0.z,y0.w, y1v.x,y1v.y,y1v.z,y1v.w};
    float aa[8] = {a0.x,a0.y,a0.z,a0.w, a1.x,a1.y,a1.z,a1.w};
    #pragma unroll
    for (int jj = 0; jj < 8; ++jj) {
      float h = fmaxf(fmaf(d, yy[jj] + aa[jj], sb[jj]), 0.f);
      s = fmaf(h, sw[jj], s);
    }
    g = batch[i];
  }
  int g0 = __shfl(g, 0);
  bool uni = __all(g == g0);
  if (uni) {
    #pragma unroll
    for (int off = 32; off > 0; off >>= 1) s += __shfl_down(s, off);
    if ((threadIdx.x & 63) == 0 && g0 >= 0) unsafeAtomicAdd(&zacc[g0], s);
  } else if (i < n) {
    unsafeAtomicAdd(&zacc[g], s);
  }
}

__global__ void k_out(const float* __restrict__ zacc, const float* __restrict__ bl,
                      float* __restrict__ out, int ng) {
  int i = blockIdx.x * BLK + threadIdx.x;
  if (i < ng) {
    float z = zacc[i] + bl[0];
    float r;
    if (z >= 0.f) { r = 1.f / (1.f + expf(-z)); }
    else          { float e = expf(z); r = e / (1.f + e); }
    out[i] = r;
  }
}

// ================= fallback (R2 proven) =================

__global__ void k_init(int* __restrict__ deg, float* __restrict__ acc,
                       float* __restrict__ zacc, int n, int accn, int ng) {
  int jj = blockIdx.x * BLK + threadIdx.x;
  if (jj < accn) acc[jj] = 0.f;
  if (jj < n) deg[jj] = 1;
  if (jj < ng) zacc[jj] = 0.f;
}

__global__ void k_deg(const int* __restrict__ dst, int* __restrict__ deg, int E) {
  int i = blockIdx.x * BLK + threadIdx.x;
  if (i < E) atomicAdd(&deg[dst[i]], 1);
}

__global__ void k_y1(const float* __restrict__ x, const float* __restrict__ W1,
                     int* __restrict__ degdis, float* __restrict__ y, int n) {
  __shared__ float sW[128];
  if (threadIdx.x < 128) sW[threadIdx.x] = W1[threadIdx.x];
  __syncthreads();
  int i = blockIdx.x * BLK + threadIdx.x;
  if (i >= n) return;
  const float4* xp = (const float4*)(x + (size_t)i * 16);
  float4 a = xp[0], bb = xp[1], cc = xp[2], d4 = xp[3];
  float xv[16] = {a.x,a.y,a.z,a.w, bb.x,bb.y,bb.z,bb.w,
                  cc.x,cc.y,cc.z,cc.w, d4.x,d4.y,d4.z,d4.w};
  float ds = rsqrtf((float)degdis[i]);
  float o[8];
  #pragma unroll
  for (int jj = 0; jj < 8; ++jj) {
    float s = 0.f;
    #pragma unroll
    for (int k = 0; k < 16; ++k) s = fmaf(xv[k], sW[k*8 + jj], s);
    o[jj] = ds * s;
  }
  ((float*)degdis)[i] = ds;
  float4* yp = (float4*)(y + (size_t)i * 8);
  yp[0] = make_float4(o[0], o[1], o[2], o[3]);
  yp[1] = make_float4(o[4], o[5], o[6], o[7]);
}

__global__ void k_scatter(const int* __restrict__ src, const int* __restrict__ dst,
                          const float* __restrict__ y, float* __restrict__ acc,
                          long long total) {
  long long t = (long long)blockIdx.x * BLK + threadIdx.x;
  if (t >= total) return;
  int e = (int)(t >> 3);
  int h = (int)(t & 7);
  int s = src[e], d = dst[e];
  unsafeAtomicAdd(&acc[(size_t)d * 8 + h], y[(size_t)s * 8 + h]);
}

// ================= host =================

static inline size_t alignup(size_t v) { return (v + 255) & ~(size_t)255; }

extern "C" void kernel_launch(void* const* d_in, const int* in_sizes, int n_in,
                              void* d_out, int out_size, void* d_ws, size_t ws_size,
                              hipStream_t stream) {
  const float* x   = (const float*)d_in[0];
  const int*   ei  = (const int*)  d_in[1];
  const int*   bat = (const int*)  d_in[2];
  const float* W1  = (const float*)d_in[3];
  const float* b1  = (const float*)d_in[4];
  const float* W2  = (const float*)d_in[5];
  const float* b2  = (const float*)d_in[6];
  const float* Wl  = (const float*)d_in[7];
  const float* bl  = (const float*)d_in[8];
  float* out = (float*)d_out;

  int n  = in_sizes[0] / 16;   // 250000
  int E  = in_sizes[1] / 2;    // 8000000
  int ng = out_size;           // 512

  const int* src = ei;
  const int* dst = ei + E;

  int nb = (n + 255) >> 8;     // 977

  char* wsb = (char*)d_ws;
  size_t offY  = alignup((size_t)n * 4);                 // dis (or deg alias)
  size_t offA  = offY + alignup((size_t)n * 8 * 4);      // y
  size_t offZ  = offA + alignup((size_t)n * 8 * 4);      // acc
  size_t offH  = offZ + alignup((size_t)ng * 4);         // zacc
  size_t offB  = offH + alignup((size_t)NBMAX * 4);      // ghist
  size_t offCu = offB + alignup((size_t)(NBMAX + 1) * 4);// base
  size_t offBn = offCu + alignup((size_t)NBMAX * 4);     // cursor
  size_t need  = offBn + alignup((size_t)E * 4);         // binned

  float* dis    = (float*)wsb;
  int*   deg    = (int*)wsb;
  float* y      = (float*)(wsb + offY);
  float* acc    = (float*)(wsb + offA);
  float* zacc   = (float*)(wsb + offZ);
  int*   ghist  = (int*)(wsb + offH);
  int*   base   = (int*)(wsb + offB);
  int*   cursor = (int*)(wsb + offCu);
  int*   binned = (int*)(wsb + offBn);

  int gN = (n + BLK - 1) / BLK;
  int gG = (ng + BLK - 1) / BLK;

  bool binpath = (ws_size >= need) && (nb <= NBMAX) && (n < (1 << 24));

  if (binpath) {
    int histChunk = 15625;
    int gHist = (int)(((long long)E + histChunk - 1) / histChunk);
    int gBin  = (int)(((long long)E + CH - 1) / CH);
    int gI0   = (NBMAX > ng ? NBMAX : ng + BLK - 1) / BLK + 1;
    k_init0 <<<gI0, BLK, 0, stream>>>(ghist, zacc, NBMAX, ng);
    k_hist  <<<gHist, BLK, 0, stream>>>(dst, ghist, E, nb, histChunk);
    k_scan  <<<1, BLK, 0, stream>>>(ghist, base, cursor, nb, E);
    k_bin   <<<gBin, BLK, 0, stream>>>(src, dst, cursor, binned, E, nb);
    k_degdis<<<nb, BLK, 0, stream>>>(base, binned, dis, n);
    k_y1n   <<<gN, BLK, 0, stream>>>(x, W1, dis, y, n);
    k_acc   <<<nb, BLK, 0, stream>>>(base, binned, y, acc, n);
    k_mid   <<<gN, BLK, 0, stream>>>(dis, y, acc, W2, b1, n, 0);
    k_acc   <<<nb, BLK, 0, stream>>>(base, binned, y, acc, n);
    k_final <<<gN, BLK, 0, stream>>>(dis, y, acc, b2, Wl, bat, zacc, n);
  } else {
    int accn = n * 8;
    long long tot = (long long)E * 8;
    int gInit = (accn + BLK - 1) / BLK;
    int gE    = (E + BLK - 1) / BLK;
    int gS    = (int)((tot + BLK - 1) / BLK);
    k_init   <<<gInit, BLK, 0, stream>>>(deg, acc, zacc, n, accn, ng);
    k_deg    <<<gE, BLK, 0, stream>>>(dst, deg, E);
    k_y1     <<<gN, BLK, 0, stream>>>(x, W1, deg, y, n);
    k_scatter<<<gS, BLK, 0, stream>>>(src, dst, y, acc, tot);
    k_mid    <<<gN, BLK, 0, stream>>>(dis, y, acc, W2, b1, n, 1);
    k_scatter<<<gS, BLK, 0, stream>>>(src, dst, y, acc, tot);
    k_final  <<<gN, BLK, 0, stream>>>(dis, y, acc, b2, Wl, bat, zacc, n);
  }
  k_out<<<gG, BLK, 0, stream>>>(zacc, bl, out, ng);
}

// Round 6
// 537.474 us; speedup vs baseline: 2.4694x; 1.6840x over previous
//
#include <hip/hip_runtime.h>
#include <math.h>

#define BLK 256
#define CH 8192          // edges per k_bin block
#define NBMAX 1024       // max buckets (256 nodes each)

// ================= binned + CSR path =================

// zero ghist + zacc; rowptr[n] = E
__global__ void k_init0(int* __restrict__ ghist, float* __restrict__ zacc,
                        int* __restrict__ rowptr, int nb, int ng, int n, int E,
                        int primary) {
  int i = blockIdx.x * BLK + threadIdx.x;
  if (i < nb) ghist[i] = 0;
  if (i < ng) zacc[i] = 0.f;
  if (primary && i == 0) rowptr[n] = E;
}

// per-bucket histogram of dst>>8
__global__ void k_hist(const int* __restrict__ dst, int* __restrict__ ghist,
                       int E, int nb, int chunk) {
  __shared__ int h[NBMAX];
  for (int i = threadIdx.x; i < NBMAX; i += BLK) h[i] = 0;
  __syncthreads();
  long long s0 = (long long)blockIdx.x * chunk;
  int c = (int)min((long long)chunk, (long long)E - s0);
  for (int i = threadIdx.x; i < c; i += BLK)
    atomicAdd(&h[dst[s0 + i] >> 8], 1);
  __syncthreads();
  for (int b = threadIdx.x; b < nb; b += BLK)
    if (h[b]) atomicAdd(&ghist[b], h[b]);
}

// exclusive scan of ghist -> base[0..nb], cursor=base
__global__ void k_scan(const int* __restrict__ ghist, int* __restrict__ base,
                       int* __restrict__ cursor, int nb, int E) {
  __shared__ int temp[BLK];
  int t = threadIdx.x;
  int v[4]; int sm = 0;
  #pragma unroll
  for (int k = 0; k < 4; ++k) {
    int idx = t * 4 + k;
    v[k] = (idx < nb) ? ghist[idx] : 0;
    sm += v[k];
  }
  temp[t] = sm; __syncthreads();
  int inc = sm;
  for (int off = 1; off < BLK; off <<= 1) {
    int u = (t >= off) ? temp[t - off] : 0; __syncthreads();
    inc += u; temp[t] = inc; __syncthreads();
  }
  int run = inc - sm;
  #pragma unroll
  for (int k = 0; k < 4; ++k) {
    int idx = t * 4 + k;
    if (idx < nb) { base[idx] = run; cursor[idx] = run; }
    run += v[k];
  }
  if (t == BLK - 1) base[nb] = E;
}

// bin edges into per-bucket segments, packed rec = (src<<8)|(dst&255)
__global__ void k_bin(const int* __restrict__ src, const int* __restrict__ dst,
                      int* __restrict__ cursor, int* __restrict__ binned,
                      int E, int nb) {
  __shared__ int cnt[NBMAX], cur[NBMAX], gofs[NBMAX], baseA[NBMAX + 1], temp[BLK];
  __shared__ int stage[CH];
  int t = threadIdx.x;
  for (int i = t; i < NBMAX; i += BLK) { cnt[i] = 0; cur[i] = 0; }
  __syncthreads();
  long long s0 = (long long)blockIdx.x * CH;
  int c = (int)min((long long)CH, (long long)E - s0);
  for (int i = t; i < c; i += BLK) atomicAdd(&cnt[dst[s0 + i] >> 8], 1);
  __syncthreads();
  int v[4], sm = 0;
  #pragma unroll
  for (int k = 0; k < 4; ++k) { v[k] = cnt[t * 4 + k]; sm += v[k]; }
  temp[t] = sm; __syncthreads();
  int inc = sm;
  for (int off = 1; off < BLK; off <<= 1) {
    int u = (t >= off) ? temp[t - off] : 0; __syncthreads();
    inc += u; temp[t] = inc; __syncthreads();
  }
  int run = inc - sm;
  #pragma unroll
  for (int k = 0; k < 4; ++k) { baseA[t * 4 + k] = run; run += v[k]; }
  if (t == BLK - 1) baseA[NBMAX] = c;
  __syncthreads();
  for (int b = t; b < nb; b += BLK)
    if (cnt[b]) gofs[b] = atomicAdd(&cursor[b], cnt[b]);
  __syncthreads();
  for (int i = t; i < c; i += BLK) {
    int d = dst[s0 + i];
    int b = d >> 8;
    int r = atomicAdd(&cur[b], 1);
    stage[baseA[b] + r] = (src[s0 + i] << 8) | (d & 255);
  }
  __syncthreads();
  for (int i = t; i < c; i += BLK) {
    int lo = 0, hi = nb;
    while (hi - lo > 1) { int m = (lo + hi) >> 1; if (baseA[m] <= i) lo = m; else hi = m; }
    binned[(size_t)gofs[lo] + (i - baseA[lo])] = stage[i];
  }
}

// per-bucket counting sort: binned run -> csr (per-node grouped), rowptr, dis
__global__ void k_sortdis(const int* __restrict__ base, const int* __restrict__ binned,
                          int* __restrict__ csr, int* __restrict__ rowptr,
                          float* __restrict__ dis, int n) {
  __shared__ int cnt[256], loff[256], cur[256], temp[BLK];
  int b = blockIdx.x, t = threadIdx.x;
  cnt[t] = 0; cur[t] = 0;
  __syncthreads();
  int s = base[b], e = base[b + 1];
  for (int i = s + t; i < e; i += BLK) atomicAdd(&cnt[binned[i] & 255], 1);
  __syncthreads();
  int v = cnt[t];
  temp[t] = v; __syncthreads();
  int inc = v;
  for (int off = 1; off < BLK; off <<= 1) {
    int u = (t >= off) ? temp[t - off] : 0; __syncthreads();
    inc += u; temp[t] = inc; __syncthreads();
  }
  loff[t] = inc - v;
  int node = b * 256 + t;
  if (node < n) {
    rowptr[node] = s + inc - v;
    dis[node] = rsqrtf((float)(v + 1));   // +1 self-loop
  }
  __syncthreads();
  for (int i = s + t; i < e; i += BLK) {
    int rec = binned[i];
    int L = rec & 255;
    int p = atomicAdd(&cur[L], 1);
    csr[s + loff[L] + p] = rec >> 8;      // scattered 4B inside 32KB window -> L2 absorbs
  }
}

// gather: acc[node][h] = sum over in-edges of y[src][h]  (atomic-free)
__global__ void k_gather(const int* __restrict__ rowptr, const int* __restrict__ csr,
                         const float* __restrict__ y, float* __restrict__ acc, int n) {
  int t = blockIdx.x * BLK + threadIdx.x;
  int node = t >> 3;
  int h = t & 7;
  if (node >= n) return;
  int start = rowptr[node];
  int end = rowptr[node + 1];
  float s = 0.f;
  int si = (start < end) ? csr[start] : 0;
  for (int k = start; k < end; ++k) {
    int nsi = (k + 1 < end) ? csr[k + 1] : 0;
    s += y[(size_t)si * 8 + h];
    si = nsi;
  }
  acc[(size_t)node * 8 + h] = s;
}

// ================= tier-2 fallback (R5 proven) =================

__global__ void k_degdis(const int* __restrict__ base, const int* __restrict__ binned,
                         float* __restrict__ dis, int n) {
  __shared__ int deg[256];
  int b = blockIdx.x, t = threadIdx.x;
  deg[t] = 1;
  __syncthreads();
  int s = base[b], e = base[b + 1];
  for (int i = s + t; i < e; i += BLK) atomicAdd(&deg[binned[i] & 255], 1);
  __syncthreads();
  int node = b * 256 + t;
  if (node < n) dis[node] = rsqrtf((float)deg[t]);
}

__global__ void k_acc(const int* __restrict__ base, const int* __restrict__ binned,
                      const float* __restrict__ y, float* __restrict__ acc, int n) {
  __shared__ float fa[2048];
  int b = blockIdx.x, t = threadIdx.x;
  for (int i = t; i < 2048; i += BLK) fa[i] = 0.f;
  __syncthreads();
  int s = base[b], e = base[b + 1];
  int j = t & 7;
  for (int i = s + (t >> 3); i < e; i += 32) {
    int rec = binned[i];
    atomicAdd(&fa[(rec & 255) * 8 + j], y[(size_t)(rec >> 8) * 8 + j]);
  }
  __syncthreads();
  int node0 = b * 256;
  int lim = (n - node0 < 256 ? n - node0 : 256) * 8;
  for (int i = t; i < lim; i += BLK) acc[(size_t)node0 * 8 + i] = fa[i];
}

// ================= dense stages =================

__global__ void k_y1n(const float* __restrict__ x, const float* __restrict__ W1,
                      const float* __restrict__ dis, float* __restrict__ y, int n) {
  __shared__ float sW[128];
  if (threadIdx.x < 128) sW[threadIdx.x] = W1[threadIdx.x];
  __syncthreads();
  int i = blockIdx.x * BLK + threadIdx.x;
  if (i >= n) return;
  const float4* xp = (const float4*)(x + (size_t)i * 16);
  float4 a = xp[0], bb = xp[1], cc = xp[2], d4 = xp[3];
  float xv[16] = {a.x,a.y,a.z,a.w, bb.x,bb.y,bb.z,bb.w,
                  cc.x,cc.y,cc.z,cc.w, d4.x,d4.y,d4.z,d4.w};
  float ds = dis[i];
  float o[8];
  #pragma unroll
  for (int jj = 0; jj < 8; ++jj) {
    float s = 0.f;
    #pragma unroll
    for (int k = 0; k < 16; ++k) s = fmaf(xv[k], sW[k*8 + jj], s);
    o[jj] = ds * s;
  }
  float4* yp = (float4*)(y + (size_t)i * 8);
  yp[0] = make_float4(o[0], o[1], o[2], o[3]);
  yp[1] = make_float4(o[4], o[5], o[6], o[7]);
}

__global__ void k_mid(const float* __restrict__ dis, float* __restrict__ y,
                      float* __restrict__ acc, const float* __restrict__ W2,
                      const float* __restrict__ b1, int n, int zero_acc) {
  __shared__ float sW[64];
  __shared__ float sb[8];
  if (threadIdx.x < 64) sW[threadIdx.x] = W2[threadIdx.x];
  if (threadIdx.x < 8)  sb[threadIdx.x] = b1[threadIdx.x];
  __syncthreads();
  int i = blockIdx.x * BLK + threadIdx.x;
  if (i >= n) return;
  float d = dis[i];
  float4* yp = (float4*)(y + (size_t)i * 8);
  float4* ap = (float4*)(acc + (size_t)i * 8);
  float4 y0 = yp[0], y1v = yp[1], a0 = ap[0], a1 = ap[1];
  float yy[8] = {y0.x,y0.y,y0.z,y0.w, y1v.x,y1v.y,y1v.z,y1v.w};
  float aa[8] = {a0.x,a0.y,a0.z,a0.w, a1.x,a1.y,a1.z,a1.w};
  float hv[8];
  #pragma unroll
  for (int jj = 0; jj < 8; ++jj) hv[jj] = fmaxf(fmaf(d, yy[jj] + aa[jj], sb[jj]), 0.f);
  float o[8];
  #pragma unroll
  for (int jj = 0; jj < 8; ++jj) {
    float s = 0.f;
    #pragma unroll
    for (int k = 0; k < 8; ++k) s = fmaf(hv[k], sW[k*8 + jj], s);
    o[jj] = d * s;
  }
  yp[0] = make_float4(o[0], o[1], o[2], o[3]);
  yp[1] = make_float4(o[4], o[5], o[6], o[7]);
  if (zero_acc) {
    ap[0] = make_float4(0.f, 0.f, 0.f, 0.f);
    ap[1] = make_float4(0.f, 0.f, 0.f, 0.f);
  }
}

__global__ void k_final(const float* __restrict__ dis, const float* __restrict__ y,
                        const float* __restrict__ acc, const float* __restrict__ b2,
                        const float* __restrict__ Wl, const int* __restrict__ batch,
                        float* __restrict__ zacc, int n) {
  __shared__ float sb[8], sw[8];
  if (threadIdx.x < 8) { sb[threadIdx.x] = b2[threadIdx.x]; sw[threadIdx.x] = Wl[threadIdx.x]; }
  __syncthreads();
  int i = blockIdx.x * BLK + threadIdx.x;
  float s = 0.f;
  int g = -1;
  if (i < n) {
    float d = dis[i];
    const float4* yp = (const float4*)(y + (size_t)i * 8);
    const float4* ap = (const float4*)(acc + (size_t)i * 8);
    float4 y0 = yp[0], y1v = yp[1], a0 = ap[0], a1 = ap[1];
    float yy[8] = {y0.x,y0.y,y0.z,y0.w, y1v.x,y1v.y,y1v.z,y1v.w};
    float aa[8] = {a0.x,a0.y,a0.z,a0.w, a1.x,a1.y,a1.z,a1.w};
    #pragma unroll
    for (int jj = 0; jj < 8; ++jj) {
      float h = fmaxf(fmaf(d, yy[jj] + aa[jj], sb[jj]), 0.f);
      s = fmaf(h, sw[jj], s);
    }
    g = batch[i];
  }
  int g0 = __shfl(g, 0);
  bool uni = __all(g == g0);
  if (uni) {
    #pragma unroll
    for (int off = 32; off > 0; off >>= 1) s += __shfl_down(s, off);
    if ((threadIdx.x & 63) == 0 && g0 >= 0) unsafeAtomicAdd(&zacc[g0], s);
  } else if (i < n) {
    unsafeAtomicAdd(&zacc[g], s);
  }
}

__global__ void k_out(const float* __restrict__ zacc, const float* __restrict__ bl,
                      float* __restrict__ out, int ng) {
  int i = blockIdx.x * BLK + threadIdx.x;
  if (i < ng) {
    float z = zacc[i] + bl[0];
    float r;
    if (z >= 0.f) { r = 1.f / (1.f + expf(-z)); }
    else          { float e = expf(z); r = e / (1.f + e); }
    out[i] = r;
  }
}

// ================= tier-3 fallback (R2 proven) =================

__global__ void k_init(int* __restrict__ deg, float* __restrict__ acc,
                       float* __restrict__ zacc, int n, int accn, int ng) {
  int jj = blockIdx.x * BLK + threadIdx.x;
  if (jj < accn) acc[jj] = 0.f;
  if (jj < n) deg[jj] = 1;
  if (jj < ng) zacc[jj] = 0.f;
}

__global__ void k_deg(const int* __restrict__ dst, int* __restrict__ deg, int E) {
  int i = blockIdx.x * BLK + threadIdx.x;
  if (i < E) atomicAdd(&deg[dst[i]], 1);
}

__global__ void k_y1(const float* __restrict__ x, const float* __restrict__ W1,
                     int* __restrict__ degdis, float* __restrict__ y, int n) {
  __shared__ float sW[128];
  if (threadIdx.x < 128) sW[threadIdx.x] = W1[threadIdx.x];
  __syncthreads();
  int i = blockIdx.x * BLK + threadIdx.x;
  if (i >= n) return;
  const float4* xp = (const float4*)(x + (size_t)i * 16);
  float4 a = xp[0], bb = xp[1], cc = xp[2], d4 = xp[3];
  float xv[16] = {a.x,a.y,a.z,a.w, bb.x,bb.y,bb.z,bb.w,
                  cc.x,cc.y,cc.z,cc.w, d4.x,d4.y,d4.z,d4.w};
  float ds = rsqrtf((float)degdis[i]);
  float o[8];
  #pragma unroll
  for (int jj = 0; jj < 8; ++jj) {
    float s = 0.f;
    #pragma unroll
    for (int k = 0; k < 16; ++k) s = fmaf(xv[k], sW[k*8 + jj], s);
    o[jj] = ds * s;
  }
  ((float*)degdis)[i] = ds;
  float4* yp = (float4*)(y + (size_t)i * 8);
  yp[0] = make_float4(o[0], o[1], o[2], o[3]);
  yp[1] = make_float4(o[4], o[5], o[6], o[7]);
}

__global__ void k_scatter(const int* __restrict__ src, const int* __restrict__ dst,
                          const float* __restrict__ y, float* __restrict__ acc,
                          long long total) {
  long long t = (long long)blockIdx.x * BLK + threadIdx.x;
  if (t >= total) return;
  int e = (int)(t >> 3);
  int h = (int)(t & 7);
  int s = src[e], d = dst[e];
  unsafeAtomicAdd(&acc[(size_t)d * 8 + h], y[(size_t)s * 8 + h]);
}

// ================= host =================

static inline size_t alignup(size_t v) { return (v + 255) & ~(size_t)255; }

extern "C" void kernel_launch(void* const* d_in, const int* in_sizes, int n_in,
                              void* d_out, int out_size, void* d_ws, size_t ws_size,
                              hipStream_t stream) {
  const float* x   = (const float*)d_in[0];
  const int*   ei  = (const int*)  d_in[1];
  const int*   bat = (const int*)  d_in[2];
  const float* W1  = (const float*)d_in[3];
  const float* b1  = (const float*)d_in[4];
  const float* W2  = (const float*)d_in[5];
  const float* b2  = (const float*)d_in[6];
  const float* Wl  = (const float*)d_in[7];
  const float* bl  = (const float*)d_in[8];
  float* out = (float*)d_out;

  int n  = in_sizes[0] / 16;   // 250000
  int E  = in_sizes[1] / 2;    // 8000000
  int ng = out_size;           // 512

  const int* src = ei;
  const int* dst = ei + E;

  int nb = (n + 255) >> 8;     // 977

  char* wsb = (char*)d_ws;
  size_t offY  = alignup((size_t)n * 4);                  // dis
  size_t offA  = offY + alignup((size_t)n * 8 * 4);       // y
  size_t offZ  = offA + alignup((size_t)n * 8 * 4);       // acc
  size_t offH  = offZ + alignup((size_t)ng * 4);          // zacc
  size_t offB  = offH + alignup((size_t)NBMAX * 4);       // ghist
  size_t offCu = offB + alignup((size_t)(NBMAX + 1) * 4); // base
  size_t offBn = offCu + alignup((size_t)NBMAX * 4);      // cursor
  size_t offRp = offBn + alignup((size_t)E * 4);          // binned
  size_t offCs = offRp + alignup(((size_t)n + 1) * 4);    // rowptr
  size_t need1 = offCs + alignup((size_t)E * 4);          // csr
  size_t need2 = offRp;                                   // tier-2: through binned

  float* dis    = (float*)wsb;
  int*   deg    = (int*)wsb;
  float* y      = (float*)(wsb + offY);
  float* acc    = (float*)(wsb + offA);
  float* zacc   = (float*)(wsb + offZ);
  int*   ghist  = (int*)(wsb + offH);
  int*   base   = (int*)(wsb + offB);
  int*   cursor = (int*)(wsb + offCu);
  int*   binned = (int*)(wsb + offBn);
  int*   rowptr = (int*)(wsb + offRp);
  int*   csr    = (int*)(wsb + offCs);

  int gN = (n + BLK - 1) / BLK;
  int gG = (ng + BLK - 1) / BLK;
  int gT = (n * 8 + BLK - 1) / BLK;

  bool ok_bin = (nb <= NBMAX) && (n < (1 << 23));
  bool tier1 = ok_bin && (ws_size >= need1);
  bool tier2 = ok_bin && (ws_size >= need2);

  if (tier1 || tier2) {
    int histChunk = 15625;
    int gHist = (int)(((long long)E + histChunk - 1) / histChunk);
    int gBin  = (int)(((long long)E + CH - 1) / CH);
    int gI0   = (NBMAX > ng ? NBMAX : ng) / BLK + 1;
    k_init0 <<<gI0, BLK, 0, stream>>>(ghist, zacc, rowptr, NBMAX, ng, n, E, tier1 ? 1 : 0);
    k_hist  <<<gHist, BLK, 0, stream>>>(dst, ghist, E, nb, histChunk);
    k_scan  <<<1, BLK, 0, stream>>>(ghist, base, cursor, nb, E);
    k_bin   <<<gBin, BLK, 0, stream>>>(src, dst, cursor, binned, E, nb);
    if (tier1) {
      k_sortdis<<<nb, BLK, 0, stream>>>(base, binned, csr, rowptr, dis, n);
      k_y1n   <<<gN, BLK, 0, stream>>>(x, W1, dis, y, n);
      k_gather<<<gT, BLK, 0, stream>>>(rowptr, csr, y, acc, n);
      k_mid   <<<gN, BLK, 0, stream>>>(dis, y, acc, W2, b1, n, 0);
      k_gather<<<gT, BLK, 0, stream>>>(rowptr, csr, y, acc, n);
    } else {
      k_degdis<<<nb, BLK, 0, stream>>>(base, binned, dis, n);
      k_y1n   <<<gN, BLK, 0, stream>>>(x, W1, dis, y, n);
      k_acc   <<<nb, BLK, 0, stream>>>(base, binned, y, acc, n);
      k_mid   <<<gN, BLK, 0, stream>>>(dis, y, acc, W2, b1, n, 0);
      k_acc   <<<nb, BLK, 0, stream>>>(base, binned, y, acc, n);
    }
    k_final <<<gN, BLK, 0, stream>>>(dis, y, acc, b2, Wl, bat, zacc, n);
  } else {
    int accn = n * 8;
    long long tot = (long long)E * 8;
    int gInit = (accn + BLK - 1) / BLK;
    int gE    = (E + BLK - 1) / BLK;
    int gS    = (int)((tot + BLK - 1) / BLK);
    k_init   <<<gInit, BLK, 0, stream>>>(deg, acc, zacc, n, accn, ng);
    k_deg    <<<gE, BLK, 0, stream>>>(dst, deg, E);
    k_y1     <<<gN, BLK, 0, stream>>>(x, W1, deg, y, n);
    k_scatter<<<gS, BLK, 0, stream>>>(src, dst, y, acc, tot);
    k_mid    <<<gN, BLK, 0, stream>>>(dis, y, acc, W2, b1, n, 1);
    k_scatter<<<gS, BLK, 0, stream>>>(src, dst, y, acc, tot);
    k_final  <<<gN, BLK, 0, stream>>>(dis, y, acc, b2, Wl, bat, zacc, n);
  }
  k_out<<<gG, BLK, 0, stream>>>(zacc, bl, out, ng);
}